// Round 10
// baseline (157.714 us; speedup 1.0000x reference)
//
#include <hip/hip_runtime.h>
#include <cmath>

#define BB 4
#define TT 8192
#define DD 1024
#define DBLK 32              // d's per chain
#define NDB (DD/DBLK)        // 32 d-blocks
#define NCHAIN (BB*NDB)      // 128 chains (b, dblk)
#define NG 8                 // groups (blocks) per chain
#define GL (TT/NG)           // 1024 timesteps per block
#define NSEG 4               // segments per group
#define SL (GL/NSEG)         // 256 timesteps per segment
#define NPART 8              // wave-parts per segment (tid>>5)
#define PLEN (SL/NPART)      // 32 steps per part-slot
#define NSLOT (NSEG*NPART)   // 32 slots per group
#define NBLK (NCHAIN*NG)     // 1024 blocks == one co-resident generation

typedef unsigned long long u64;

// y[b,t,d] = Re(h[t]),  h[t] = r*h[t-1] + x[t],  r = exp(-|a_d|) * cis(w_d)
//
// R9 lesson: occupancy wasn't the lever; per-chunk sync (32 publishes/chain,
// O(NCH^2) walk reads, generation lockstep) was. This version: 1024-step
// groups -> 8 publishes/chain, walk <= 7 slots, all 1024 blocks co-resident.
// Pass A: aggregate-only scan (4 segments x 8 parts + 32-lane stitch,
//         exclusive slot offsets -> LDS), publish group aggregate.
// Walk:   <=7 preds, one batched sc1 load + Horner with M=r^1024.
// Pass B: re-read x (L3-hot), scan DIRECTLY from true seed, nt-store y.
// No LDS x tile (regs only, ~10KB LDS total); pass B barrier-free.
// Fence-free sc1 protocol from R7 (RELAXED agent atomics + wave-local
// s_waitcnt vmcnt(0) payload->flag ordering; no cache-maintenance ops).

__global__ __launch_bounds__(256, 4) void fftconv_fused(
    const float* __restrict__ x, const float* __restrict__ decay,
    const float* __restrict__ freq, float2* __restrict__ agg,
    unsigned* __restrict__ flags, float* __restrict__ y)
{
    __shared__ float2 Ssub[NPART][DBLK];   // 2 KB  per-segment part aggregates
    __shared__ float2 eoff[NSLOT][DBLK];   // 8 KB  exclusive local state per slot
    __shared__ float2 Ebc[DBLK];           // 256 B incoming-state broadcast

    const int tid  = threadIdx.x;
    const int l32  = tid & 31;             // d-lane
    const int part = tid >> 5;             // 0..7
    const int bid  = blockIdx.x;
    const int g     = bid & (NG-1);        // group index (low bits: dispatch order)
    const int chain = bid >> 3;            // NG=8
    const int dblk  = chain & (NDB-1);
    const int b     = chain >> 5;          // NDB=32

    const int d = dblk*DBLK + l32;

    // per-d constants (powers built by direct exp/sincos; args <= ~5e3 rad,
    // same error profile as R7-R9 which passed at absmax 0.5)
    const float a = fabsf(decay[d]);
    const float w = freq[d];
    float s_, c_;
    float e = expf(-a); sincosf(w, &s_, &c_);
    const float rr = e*c_, ri = e*s_;                         // r
    e = expf(-a*(float)PLEN); sincosf(w*(float)PLEN, &s_, &c_);
    const float Msr = e*c_, Msi = e*s_;                       // r^32 (slot step)
    e = expf(-a*(float)SL); sincosf(w*(float)SL, &s_, &c_);
    const float Mgr = e*c_, Mgi = e*s_;                       // r^256 (segment step)
    e = expf(-a*(float)GL); sincosf(w*(float)GL, &s_, &c_);
    const float MGr = e*c_, MGi = e*s_;                       // r^1024 (group step)
    e = expf(-a*(float)(PLEN*part)); sincosf(w*(float)(PLEN*part), &s_, &c_);
    const float Mpr = e*c_, Mpi = e*s_;                       // r^(32*part)

    const size_t gbase = ((size_t)(b*TT + g*GL))*DD + d;
    const float* xbase = x + gbase;

    // ---------------- pass A: aggregate-only scan ----------------
    float Lr = 0.f, Li = 0.f;              // running local state (tid<32 only)
    for (int s = 0; s < NSEG; ++s) {
        const float* xp = xbase + (size_t)(s*SL + part*PLEN)*DD;
        float hr = 0.f, hi = 0.f;
#pragma unroll
        for (int t = 0; t < PLEN; ++t) {
            float xv = xp[(size_t)t*DD];
            float nr = fmaf(rr, hr, fmaf(-ri, hi, xv));
            hi = fmaf(rr, hi, ri*hr);
            hr = nr;
        }
        Ssub[part][l32] = make_float2(hr, hi);
        __syncthreads();
        if (tid < 32) {
#pragma unroll
            for (int p = 0; p < NPART; ++p) {
                eoff[s*NPART + p][l32] = make_float2(Lr, Li);
                float2 Sp = Ssub[p][l32];
                float nr = fmaf(Msr, Lr, fmaf(-Msi, Li, Sp.x));
                Li = fmaf(Msr, Li, fmaf(Msi, Lr, Sp.y));
                Lr = nr;
            }
        }
        __syncthreads();                   // Ssub reused next segment
    }

    // ---------------- publish + lookback (tid<32) ----------------
    if (tid < 32) {
        float2 Av = make_float2(Lr, Li);   // group aggregate (zero-seeded)
        u64 raw; __builtin_memcpy(&raw, &Av, 8);
        __hip_atomic_store(reinterpret_cast<u64*>(&agg[(size_t)bid*DBLK + l32]),
                           raw, __ATOMIC_RELAXED, __HIP_MEMORY_SCOPE_AGENT);
        asm volatile("s_waitcnt vmcnt(0)" ::: "memory");  // payload before flag
        if (l32 == 0)
            __hip_atomic_store(&flags[bid], 1u, __ATOMIC_RELAXED,
                               __HIP_MEMORY_SCOPE_AGENT);

        const int cbase = chain*NG;        // == bid - g
        if (l32 < g) {                     // lane-parallel poll, <=7 flags
            while (__hip_atomic_load(&flags[cbase + l32], __ATOMIC_RELAXED,
                                     __HIP_MEMORY_SCOPE_AGENT) == 0u) {
                __builtin_amdgcn_s_sleep(1);
            }
        }
        asm volatile("" ::: "memory");     // keep payload loads below the poll

        float Er = 0.f, Ei = 0.f;
        u64 q[NG-1];
#pragma unroll
        for (int j = 0; j < NG-1; ++j)
            if (j < g)
                q[j] = __hip_atomic_load(
                    reinterpret_cast<u64*>(&agg[(size_t)(cbase + j)*DBLK + l32]),
                    __ATOMIC_RELAXED, __HIP_MEMORY_SCOPE_AGENT);
#pragma unroll
        for (int j = 0; j < NG-1; ++j) {
            if (j < g) {
                float2 A; __builtin_memcpy(&A, &q[j], 8);
                float nr = fmaf(MGr, Er, fmaf(-MGi, Ei, A.x));
                Ei = fmaf(MGr, Ei, fmaf(MGi, Er, A.y));
                Er = nr;
            }
        }
        Ebc[l32] = make_float2(Er, Ei);    // incoming state for this group
    }
    __syncthreads();

    // ---------------- pass B: seeded rescan, write y (no barriers) --------
    {
        float2 Ev = Ebc[l32];
        // F = r^(32*part) * E; advanced by r^256 per segment
        float Fr = Mpr*Ev.x - Mpi*Ev.y;
        float Fi = Mpr*Ev.y + Mpi*Ev.x;
        float* ybase = y + gbase;
        for (int s = 0; s < NSEG; ++s) {
            float2 eo = eoff[s*NPART + part][l32];
            float hr = eo.x + Fr;          // true state BEFORE this slot
            float hi = eo.y + Fi;
            const float* xp = xbase + (size_t)(s*SL + part*PLEN)*DD;
            float*       yp = ybase + (size_t)(s*SL + part*PLEN)*DD;
#pragma unroll
            for (int t = 0; t < PLEN; ++t) {
                float xv = xp[(size_t)t*DD];
                float nr = fmaf(rr, hr, fmaf(-ri, hi, xv));
                hi = fmaf(rr, hi, ri*hr);
                hr = nr;
                __builtin_nontemporal_store(hr, yp + (size_t)t*DD);
            }
            float nFr = Mgr*Fr - Mgi*Fi;   // F *= r^256
            Fi = Mgr*Fi + Mgi*Fr;
            Fr = nFr;
        }
    }
}

extern "C" void kernel_launch(void* const* d_in, const int* in_sizes, int n_in,
                              void* d_out, int out_size, void* d_ws, size_t ws_size,
                              hipStream_t stream) {
    const float* x     = (const float*)d_in[0];
    const float* decay = (const float*)d_in[1];
    const float* freq  = (const float*)d_in[2];
    float*       y     = (float*)d_out;

    float2*   agg   = (float2*)d_ws;                          // 1024*32*8 = 256 KB
    unsigned* flags = (unsigned*)((char*)d_ws + (size_t)NBLK*DBLK*sizeof(float2));

    // zero the lookback flags each launch (capture-legal async memset);
    // kernel-boundary implicit release makes the zeros visible to sc1 reads.
    (void)hipMemsetAsync(flags, 0, NBLK*sizeof(unsigned), stream);
    fftconv_fused<<<NBLK, 256, 0, stream>>>(x, decay, freq, agg, flags, y);
}

// Round 11
// 70.805 us; speedup vs baseline: 2.2274x; 2.2274x over previous
//
#include <hip/hip_runtime.h>
#include <cmath>

#define BB 4
#define TT 8192
#define DD 1024
#define CL 256               // timesteps per pair (chunk)
#define DBLK 32              // d's per chain
#define NCH (TT/CL)          // 32 chunks per chain
#define NDB (DD/DBLK)        // 32 d-blocks
#define NCHAIN (BB*NDB)      // 128 chains
#define NPAIR (NCHAIN*NCH)   // 4096 (chain,chunk) pairs
#define GRID 1024            // 4 blocks/CU -> fully co-resident
#define NITER (NPAIR/GRID)   // 4 iterations per block
#define NPART 8              // t-parts (32 lanes each)
#define PLEN (CL/NPART)      // 32 steps per part

typedef unsigned long long u64;

// y[b,t,d] = Re(h[t]),  h[t] = r*h[t-1] + x[t],  r = exp(-|a_d|) * cis(w_d)
//
// R10 lesson: dropping the LDS tile doubled HBM x-traffic. R9 lesson:
// traffic-ideal lockstep phases cap at ~3.1 TB/s. This version = R9's
// proven pieces + persistent 4-iteration pipeline: the finish phase reads
// only registers, so the tile is dead after the scan -> issue next
// iteration's stage (global_load_lds) into the SAME buffer right after the
// scan barrier; those HBM reads overlap the walk + y-writes.
// Fence-free sc1 protocol (R7): RELAXED agent atomics, payload->flag via
// wave-local s_waitcnt vmcnt(0), zero cache-maintenance ops.

__global__ __launch_bounds__(256, 4) void fftconv_fused(
    const float* __restrict__ x, const float* __restrict__ decay,
    const float* __restrict__ freq, float2* __restrict__ agg,
    unsigned* __restrict__ flags, float* __restrict__ y)
{
    __shared__ float tile[CL*DBLK];        // 32 KB
    __shared__ float2 Ssub[NPART][DBLK];   // 2 KB
    __shared__ float2 eoff[NPART][DBLK];   // 2 KB
    __shared__ float2 Ebc[DBLK];           // 256 B

    const int tid  = threadIdx.x;
    const int l32  = tid & 31;             // d-lane
    const int part = tid >> 5;             // 0..7 (t-part)
    const int wv   = tid >> 6;             // wave 0..3
    const int wl   = tid & 63;             // lane in wave
    const int bid  = blockIdx.x;

    // issue one chunk's x tile into LDS: 8 global_load_lds x4 per wave.
    // lane l of a wave writes LDS base + l*16 (HW rule) == rows t0..t0+7
    // of the [256][32] float tile; global src = matching x address.
    auto stage = [&](int pair) {
        const int c     = pair & (NCH-1);
        const int chain = pair >> 5;
        const int dblk  = chain & (NDB-1);
        const int b     = chain >> 5;
        const float* xb = x + ((size_t)(b*TT + c*CL))*DD + dblk*DBLK;
        const float* gp0 = xb + (size_t)(wl >> 3)*DD + ((wl & 7) << 2);
#pragma unroll
        for (int i = 0; i < 8; ++i) {
            const int t0 = wv*64 + i*8;
            __builtin_amdgcn_global_load_lds(
                (const __attribute__((address_space(1))) void*)(gp0 + (size_t)t0*DD),
                (__attribute__((address_space(3))) void*)&tile[t0*DBLK],
                16, 0, 0);
        }
    };

    stage(bid);                            // prologue: iteration 0's tile

    for (int k = 0; k < NITER; ++k) {
        const int pair  = k*GRID + bid;
        const int c     = pair & (NCH-1);
        const int chain = pair >> 5;
        const int dblk  = chain & (NDB-1);
        const int b     = chain >> 5;
        const int d     = dblk*DBLK + l32;

        // per-d constants (chain changes each iteration)
        const float a = fabsf(decay[d]);
        const float w = freq[d];
        float s_, c_;
        float e = expf(-a); sincosf(w, &s_, &c_);
        const float rr = e*c_, ri = e*s_;                       // r
        e = expf(-a*(float)PLEN); sincosf(w*(float)PLEN, &s_, &c_);
        const float Msr = e*c_, Msi = e*s_;                     // r^32
        e = expf(-a*(float)CL); sincosf(w*(float)CL, &s_, &c_);
        const float Mr = e*c_, Mi = e*s_;                       // r^256
        e = expf(-a*(float)(PLEN*part)); sincosf(w*(float)(PLEN*part), &s_, &c_);
        const float Mpr = e*c_, Mpi = e*s_;                     // r^(32*part)

        asm volatile("s_waitcnt vmcnt(0)" ::: "memory");        // tile landed
        __syncthreads();

        // ---- local scan from zero; real-part history in registers ----
        float hRr[PLEN];
        {
            float hr = 0.f, hi = 0.f;
            const int rowbase = part*PLEN;
#pragma unroll
            for (int t = 0; t < PLEN; ++t) {
                float xv = tile[(rowbase + t)*DBLK + l32];
                float nr = fmaf(rr, hr, fmaf(-ri, hi, xv));
                hi = fmaf(rr, hi, ri*hr);
                hr = nr;
                hRr[t] = hr;
            }
            Ssub[part][l32] = make_float2(hr, hi);
        }
        __syncthreads();                   // tile fully consumed by all waves

        // ---- overlap: issue NEXT iteration's tile into the same buffer ----
        if (k + 1 < NITER) stage((k+1)*GRID + bid);

        // ---- tid<32: stitch, publish, poll, walk ----
        if (tid < 32) {
            float Lr = 0.f, Li = 0.f;
#pragma unroll
            for (int p = 0; p < NPART; ++p) {
                eoff[p][l32] = make_float2(Lr, Li);
                float2 Sp = Ssub[p][l32];
                float nr = fmaf(Msr, Lr, fmaf(-Msi, Li, Sp.x));
                Li = fmaf(Msr, Li, fmaf(Msi, Lr, Sp.y));
                Lr = nr;
            }
            float2 Av = make_float2(Lr, Li);   // chunk aggregate (zero-seeded)
            u64 raw; __builtin_memcpy(&raw, &Av, 8);
            __hip_atomic_store(reinterpret_cast<u64*>(&agg[(size_t)pair*DBLK + l32]),
                               raw, __ATOMIC_RELAXED, __HIP_MEMORY_SCOPE_AGENT);
            asm volatile("s_waitcnt vmcnt(0)" ::: "memory");    // payload before flag
            if (l32 == 0)
                __hip_atomic_store(&flags[pair], 1u, __ATOMIC_RELAXED,
                                   __HIP_MEMORY_SCOPE_AGENT);

            const int cbase = chain*NCH;   // == pair - c
            if (l32 < c) {                 // lane-parallel poll (c <= 31)
                while (__hip_atomic_load(&flags[cbase + l32], __ATOMIC_RELAXED,
                                         __HIP_MEMORY_SCOPE_AGENT) == 0u) {
                    __builtin_amdgcn_s_sleep(1);
                }
            }
            asm volatile("" ::: "memory");

            float Er = 0.f, Ei = 0.f;
            int j = 0;
            while (j + 8 <= c) {
                u64 q[8];
#pragma unroll
                for (int t = 0; t < 8; ++t)
                    q[t] = __hip_atomic_load(
                        reinterpret_cast<u64*>(&agg[(size_t)(cbase + j + t)*DBLK + l32]),
                        __ATOMIC_RELAXED, __HIP_MEMORY_SCOPE_AGENT);
#pragma unroll
                for (int t = 0; t < 8; ++t) {
                    float2 A; __builtin_memcpy(&A, &q[t], 8);
                    float nr = fmaf(Mr, Er, fmaf(-Mi, Ei, A.x));
                    Ei = fmaf(Mr, Ei, fmaf(Mi, Er, A.y));
                    Er = nr;
                }
                j += 8;
            }
            for (; j < c; ++j) {
                u64 raw2 = __hip_atomic_load(
                    reinterpret_cast<u64*>(&agg[(size_t)(cbase + j)*DBLK + l32]),
                    __ATOMIC_RELAXED, __HIP_MEMORY_SCOPE_AGENT);
                float2 A; __builtin_memcpy(&A, &raw2, 8);
                float nr = fmaf(Mr, Er, fmaf(-Mi, Ei, A.x));
                Ei = fmaf(Mr, Ei, fmaf(Mi, Er, A.y));
                Er = nr;
            }
            Ebc[l32] = make_float2(Er, Ei);
        }
        __syncthreads();

        // ---- finish (registers only; stage loads still in flight) ----
        {
            float2 Ev = Ebc[l32];
            float2 ev = eoff[part][l32];
            float Sr = ev.x + (Mpr*Ev.x - Mpi*Ev.y);
            float Si = ev.y + (Mpr*Ev.y + Mpi*Ev.x);
            float wr = rr*Sr - ri*Si;      // w = r * S
            float wi = rr*Si + ri*Sr;
            float* yp = y + ((size_t)(b*TT + c*CL))*DD + dblk*DBLK
                          + (size_t)(part*PLEN)*DD + l32;
#pragma unroll
            for (int t = 0; t < PLEN; ++t) {
                __builtin_nontemporal_store(hRr[t] + wr, yp);
                yp += DD;
                float nwr = rr*wr - ri*wi; // w *= r
                wi = rr*wi + ri*wr;
                wr = nwr;
            }
        }
        // loop top: vmcnt(0) + barrier gate the next scan on the new tile
    }
}

extern "C" void kernel_launch(void* const* d_in, const int* in_sizes, int n_in,
                              void* d_out, int out_size, void* d_ws, size_t ws_size,
                              hipStream_t stream) {
    const float* x     = (const float*)d_in[0];
    const float* decay = (const float*)d_in[1];
    const float* freq  = (const float*)d_in[2];
    float*       y     = (float*)d_out;

    float2*   agg   = (float2*)d_ws;                          // 4096*32*8 = 1 MB
    unsigned* flags = (unsigned*)((char*)d_ws + (size_t)NPAIR*DBLK*sizeof(float2));

    // zero the lookback flags each launch (capture-legal async memset);
    // kernel-boundary implicit release makes the zeros visible to sc1 reads.
    (void)hipMemsetAsync(flags, 0, NPAIR*sizeof(unsigned), stream);
    fftconv_fused<<<GRID, 256, 0, stream>>>(x, decay, freq, agg, flags, y);
}